// Round 1
// baseline (85.914 us; speedup 1.0000x reference)
//
#include <hip/hip_runtime.h>
#include <hip/hip_bf16.h>
#include <stdint.h>

#define N_ROWS 8192
#define DIM 256
#define NUM_CLASSES 32

typedef __attribute__((ext_vector_type(4))) float f32x4;
typedef __attribute__((ext_vector_type(8))) short bf16x8;

static __device__ inline unsigned short f2bf(float f) {
  union { float f; unsigned u; } v; v.f = f;
  unsigned r = v.u + 0x7FFFu + ((v.u >> 16) & 1u);
  return (unsigned short)(r >> 16);
}

static __device__ inline void async_copy16(const void* g, void* l) {
  __builtin_amdgcn_global_load_lds(
      (const __attribute__((address_space(1))) unsigned int*)g,
      (__attribute__((address_space(3))) unsigned int*)l, 16, 0, 0);
}

// ---------------------------------------------------------------------------
// Kernel 1: L2-normalize rows, write bf16. One wave per row, 4 rows/block.
// ---------------------------------------------------------------------------
__global__ __launch_bounds__(256)
void normalize_kernel(const float* __restrict__ emb, unsigned short* __restrict__ en) {
  const int row = blockIdx.x * 4 + (threadIdx.x >> 6);
  const int lane = threadIdx.x & 63;
  const float4 v = reinterpret_cast<const float4*>(emb + (size_t)row * DIM)[lane];
  float s = v.x * v.x + v.y * v.y + v.z * v.z + v.w * v.w;
  #pragma unroll
  for (int o = 32; o; o >>= 1) s += __shfl_xor(s, o);
  const float inv = 1.0f / sqrtf(s);
  ushort4 o4;
  o4.x = f2bf(v.x * inv);
  o4.y = f2bf(v.y * inv);
  o4.z = f2bf(v.z * inv);
  o4.w = f2bf(v.w * inv);
  reinterpret_cast<ushort4*>(en + (size_t)row * DIM)[lane] = o4;
}

// ---------------------------------------------------------------------------
// Kernel 2: label histogram -> pos/neg pair counts; zero the accumulators.
// Runs every call (harness does not re-poison between replays).
// ---------------------------------------------------------------------------
__global__ void hist_kernel(const int* __restrict__ labels, float* __restrict__ acc) {
  __shared__ int cnt[NUM_CLASSES];
  if (threadIdx.x < NUM_CLASSES) cnt[threadIdx.x] = 0;
  __syncthreads();
  for (int i = threadIdx.x; i < N_ROWS; i += 256) atomicAdd(&cnt[labels[i]], 1);
  __syncthreads();
  if (threadIdx.x == 0) {
    long long pc = 0;
    for (int c = 0; c < NUM_CLASSES; ++c) pc += (long long)cnt[c] * cnt[c];
    acc[0] = 0.0f;                                        // pos_sum
    acc[1] = 0.0f;                                        // neg_sum
    acc[2] = (float)pc;                                   // pos_count
    acc[3] = (float)((long long)N_ROWS * N_ROWS - pc);    // neg_count
  }
}

// ---------------------------------------------------------------------------
// Kernel 3: fused sim = A·A^T tile GEMM + masked loss reduction.
// 128x128 tile per block, 4 waves (2x2 of 64x64), 16x16x32 bf16 MFMA.
// Triangular grid (bj >= bi), off-diagonal blocks weighted x2.
// LDS tiles XOR-swizzled (rule #21: linear gload_lds dest, inverse-swizzled
// global source, swizzled ds_read).
// ---------------------------------------------------------------------------
__global__ __launch_bounds__(256)
void sim_loss_kernel(const unsigned short* __restrict__ en,
                     const int* __restrict__ labels,
                     float* __restrict__ acc) {
  const int bj = blockIdx.x, bi = blockIdx.y;
  if (bj < bi) return;

  __shared__ __align__(16) short lA[128 * 64];
  __shared__ __align__(16) short lB[128 * 64];
  __shared__ int labA_s[128];
  __shared__ int labB_s[128];
  __shared__ float red[8];

  const int t = threadIdx.x;
  const int lane = t & 63;
  const int wid = t >> 6;
  const int rowA0 = bi * 128, rowB0 = bj * 128;

  if (t < 128) labA_s[t] = labels[rowA0 + t];
  else         labB_s[t - 128] = labels[rowB0 + (t - 128)];

  const int wm = (wid >> 1) * 64;  // wave's 64x64 sub-tile
  const int wn = (wid & 1) * 64;

  f32x4 accf[4][4];
  #pragma unroll
  for (int i = 0; i < 4; ++i)
    #pragma unroll
    for (int j = 0; j < 4; ++j) accf[i][j] = (f32x4){0.f, 0.f, 0.f, 0.f};

  for (int k0 = 0; k0 < DIM; k0 += 64) {
    // ---- stage A and B tiles: 128 rows x 64 cols bf16 = 16 KB each ----
    // linear LDS fill; global source pre-swizzled (XOR involution)
    #pragma unroll
    for (int it = 0; it < 4; ++it) {
      const int x = (it * 256 + t) * 16;       // LDS byte offset 0..16K
      const int row = x >> 7;                  // tile row (stride 128 B)
      const int q = x & 127;
      const int cb = q ^ ((row & 7) << 4);     // unswizzled col byte
      const size_t gA = ((size_t)(rowA0 + row) * DIM + k0) * 2 + cb;
      const size_t gB = ((size_t)(rowB0 + row) * DIM + k0) * 2 + cb;
      async_copy16((const char*)en + gA, (char*)lA + x);
      async_copy16((const char*)en + gB, (char*)lB + x);
    }
    __syncthreads();

    // ---- compute: 2 x (8 ds_read_b128 + 16 MFMA) ----
    #pragma unroll
    for (int kk = 0; kk < 2; ++kk) {
      const int cbase = kk * 64 + ((lane >> 4) << 4);  // k-offset bytes
      bf16x8 af[4], bf[4];
      #pragma unroll
      for (int mi = 0; mi < 4; ++mi) {
        const int row = wm + mi * 16 + (lane & 15);
        const int off = row * 128 + (cbase ^ ((row & 7) << 4));
        af[mi] = *(const bf16x8*)((const char*)lA + off);
      }
      #pragma unroll
      for (int ni = 0; ni < 4; ++ni) {
        const int row = wn + ni * 16 + (lane & 15);
        const int off = row * 128 + (cbase ^ ((row & 7) << 4));
        bf[ni] = *(const bf16x8*)((const char*)lB + off);
      }
      #pragma unroll
      for (int mi = 0; mi < 4; ++mi)
        #pragma unroll
        for (int ni = 0; ni < 4; ++ni)
          accf[mi][ni] = __builtin_amdgcn_mfma_f32_16x16x32_bf16(
              af[mi], bf[ni], accf[mi][ni], 0, 0, 0);
    }
    __syncthreads();
  }

  // ---- epilogue: masked accumulation ----
  // C/D layout: col = lane&15, row = (lane>>4)*4 + j  [m89/m91]
  float ps = 0.f, ns = 0.f;
  #pragma unroll
  for (int mi = 0; mi < 4; ++mi) {
    int lr[4];
    #pragma unroll
    for (int j = 0; j < 4; ++j)
      lr[j] = labA_s[wm + mi * 16 + ((lane >> 4) << 2) + j];
    #pragma unroll
    for (int ni = 0; ni < 4; ++ni) {
      const int lc = labB_s[wn + ni * 16 + (lane & 15)];
      #pragma unroll
      for (int j = 0; j < 4; ++j) {
        const float s = accf[mi][ni][j];
        if (lr[j] == lc) { const float d = 1.f - s; ps += d * d; }
        else             { float d = s - 1.f; d = fmaxf(d, 0.f); ns += d * d; }
      }
    }
  }
  if (bi != bj) { ps *= 2.f; ns *= 2.f; }   // symmetry weight

  #pragma unroll
  for (int o = 32; o; o >>= 1) { ps += __shfl_down(ps, o); ns += __shfl_down(ns, o); }
  if (lane == 0) { red[wid * 2] = ps; red[wid * 2 + 1] = ns; }
  __syncthreads();
  if (t == 0) {
    atomicAdd(&acc[0], red[0] + red[2] + red[4] + red[6]);
    atomicAdd(&acc[1], red[1] + red[3] + red[5] + red[7]);
  }
}

// ---------------------------------------------------------------------------
// Kernel 4: finalize scalar loss
// ---------------------------------------------------------------------------
__global__ void finalize_kernel(const float* __restrict__ acc, float* __restrict__ out) {
  out[0] = acc[0] / acc[2] + acc[1] / acc[3];
}

extern "C" void kernel_launch(void* const* d_in, const int* in_sizes, int n_in,
                              void* d_out, int out_size, void* d_ws, size_t ws_size,
                              hipStream_t stream) {
  const float* emb = (const float*)d_in[0];
  const int* labels = (const int*)d_in[1];
  float* out = (float*)d_out;

  float* acc = (float*)d_ws;                                   // 4 floats
  unsigned short* en = (unsigned short*)((char*)d_ws + 256);   // 8192x256 bf16

  normalize_kernel<<<N_ROWS / 4, 256, 0, stream>>>(emb, en);
  hist_kernel<<<1, 256, 0, stream>>>(labels, acc);
  dim3 grid(64, 64);
  sim_loss_kernel<<<grid, 256, 0, stream>>>(en, labels, acc);
  finalize_kernel<<<1, 1, 0, stream>>>(acc, out);
}

// Round 2
// 46.846 us; speedup vs baseline: 1.8340x; 1.8340x over previous
//
#include <hip/hip_runtime.h>
#include <hip/hip_bf16.h>
#include <stdint.h>

#define N_ROWS 8192
#define DIM 256
#define NUM_CLASSES 32
#define NB 64                    // 8192 / 128 tiles per side
#define NWG (NB * (NB + 1) / 2)  // 2080 triangular blocks

typedef __attribute__((ext_vector_type(4))) float f32x4;
typedef __attribute__((ext_vector_type(8))) short bf16x8;

static __device__ inline unsigned short f2bf(float f) {
  union { float f; unsigned u; } v; v.f = f;
  unsigned r = v.u + 0x7FFFu + ((v.u >> 16) & 1u);
  return (unsigned short)(r >> 16);
}

static __device__ inline void async_copy16(const void* g, void* l) {
  __builtin_amdgcn_global_load_lds(
      (const __attribute__((address_space(1))) unsigned int*)g,
      (__attribute__((address_space(3))) unsigned int*)l, 16, 0, 0);
}

// ---------------------------------------------------------------------------
// Kernel 1: L2-normalize rows, write bf16. One wave per row, 4 rows/block.
// ---------------------------------------------------------------------------
__global__ __launch_bounds__(256)
void normalize_kernel(const float* __restrict__ emb, unsigned short* __restrict__ en) {
  const int row = blockIdx.x * 4 + (threadIdx.x >> 6);
  const int lane = threadIdx.x & 63;
  const float4 v = reinterpret_cast<const float4*>(emb + (size_t)row * DIM)[lane];
  float s = v.x * v.x + v.y * v.y + v.z * v.z + v.w * v.w;
  #pragma unroll
  for (int o = 32; o; o >>= 1) s += __shfl_xor(s, o);
  const float inv = 1.0f / sqrtf(s);
  ushort4 o4;
  o4.x = f2bf(v.x * inv);
  o4.y = f2bf(v.y * inv);
  o4.z = f2bf(v.z * inv);
  o4.w = f2bf(v.w * inv);
  reinterpret_cast<ushort4*>(en + (size_t)row * DIM)[lane] = o4;
}

// ---------------------------------------------------------------------------
// Kernel 2: fused sim = A·A^T tile GEMM + masked loss partial per block.
// Triangular 1D grid (2080 blocks), 128x128 tile, 4 waves, double-buffered
// LDS (T3 2-phase), XOR-swizzled tiles, per-block partial -> parts[] (no
// atomics).
// ---------------------------------------------------------------------------
__global__ __launch_bounds__(256)
void sim_loss_kernel(const unsigned short* __restrict__ en,
                     const int* __restrict__ labels,
                     float2* __restrict__ parts) {
  // XCD-chunked bijective swizzle (NWG % 8 == 0 -> clean chunks of 260)
  const int orig = blockIdx.x;
  const int p = (orig & 7) * (NWG / 8) + (orig >> 3);

  // closed-form triangular index: cum(b) = b*(129-b)/2
  int bi = (int)((129.0f - sqrtf(16641.0f - 8.0f * (float)p)) * 0.5f);
  while ((bi + 1) * (128 - bi) / 2 <= p) ++bi;
  while (bi * (129 - bi) / 2 > p) --bi;
  const int bj = bi + (p - bi * (129 - bi) / 2);

  __shared__ __align__(16) short lA[2][128 * 64];
  __shared__ __align__(16) short lB[2][128 * 64];
  __shared__ int labA_s[128];
  __shared__ int labB_s[128];
  __shared__ float red[8];

  const int t = threadIdx.x;
  const int lane = t & 63;
  const int wid = t >> 6;
  const int rowA0 = bi * 128, rowB0 = bj * 128;

  if (t < 128) labA_s[t] = labels[rowA0 + t];
  else         labB_s[t - 128] = labels[rowB0 + (t - 128)];

  const int wm = (wid >> 1) * 64;  // wave's 64x64 sub-tile
  const int wn = (wid & 1) * 64;

  f32x4 accf[4][4];
  #pragma unroll
  for (int i = 0; i < 4; ++i)
    #pragma unroll
    for (int j = 0; j < 4; ++j) accf[i][j] = (f32x4){0.f, 0.f, 0.f, 0.f};

  // stage one 128x64 K-slice of A and B into buffer `buf`
  auto stage = [&](int buf, int k0) {
    #pragma unroll
    for (int it = 0; it < 4; ++it) {
      const int x = (it * 256 + t) * 16;       // LDS byte offset 0..16K
      const int row = x >> 7;                  // tile row (stride 128 B)
      const int q = x & 127;
      const int cb = q ^ ((row & 7) << 4);     // inverse-swizzled col byte
      const size_t gA = ((size_t)(rowA0 + row) * DIM + k0) * 2 + cb;
      const size_t gB = ((size_t)(rowB0 + row) * DIM + k0) * 2 + cb;
      async_copy16((const char*)en + gA, (char*)&lA[buf][0] + x);
      async_copy16((const char*)en + gB, (char*)&lB[buf][0] + x);
    }
  };

  stage(0, 0);
  __syncthreads();   // vmcnt(0) drain of prologue stage

  int cur = 0;
  #pragma unroll
  for (int kt = 0; kt < 4; ++kt) {
    if (kt < 3) stage(cur ^ 1, (kt + 1) * 64);   // prefetch next slice first

    #pragma unroll
    for (int kk = 0; kk < 2; ++kk) {
      const int cbase = kk * 64 + ((lane >> 4) << 4);  // k-offset bytes
      bf16x8 af[4], bf[4];
      #pragma unroll
      for (int mi = 0; mi < 4; ++mi) {
        const int row = wm + mi * 16 + (lane & 15);
        const int off = row * 128 + (cbase ^ ((row & 7) << 4));
        af[mi] = *(const bf16x8*)((const char*)&lA[cur][0] + off);
      }
      #pragma unroll
      for (int ni = 0; ni < 4; ++ni) {
        const int row = wn + ni * 16 + (lane & 15);
        const int off = row * 128 + (cbase ^ ((row & 7) << 4));
        bf[ni] = *(const bf16x8*)((const char*)&lB[cur][0] + off);
      }
      #pragma unroll
      for (int mi = 0; mi < 4; ++mi)
        #pragma unroll
        for (int ni = 0; ni < 4; ++ni)
          accf[mi][ni] = __builtin_amdgcn_mfma_f32_16x16x32_bf16(
              af[mi], bf[ni], accf[mi][ni], 0, 0, 0);
    }

    if (kt < 3) { __syncthreads(); cur ^= 1; }   // next-slice loads complete
  }

  // ---- epilogue: masked accumulation ----
  // C/D layout: col = lane&15, row = (lane>>4)*4 + j  [m89/m91]
  float ps = 0.f, ns = 0.f;
  #pragma unroll
  for (int mi = 0; mi < 4; ++mi) {
    int lr[4];
    #pragma unroll
    for (int j = 0; j < 4; ++j)
      lr[j] = labA_s[wm + mi * 16 + ((lane >> 4) << 2) + j];
    #pragma unroll
    for (int ni = 0; ni < 4; ++ni) {
      const int lc = labB_s[wn + ni * 16 + (lane & 15)];
      #pragma unroll
      for (int j = 0; j < 4; ++j) {
        const float s = accf[mi][ni][j];
        if (lr[j] == lc) { const float d = 1.f - s; ps += d * d; }
        else             { float d = s - 1.f; d = fmaxf(d, 0.f); ns += d * d; }
      }
    }
  }
  if (bi != bj) { ps *= 2.f; ns *= 2.f; }   // symmetry weight

  #pragma unroll
  for (int o = 32; o; o >>= 1) { ps += __shfl_down(ps, o); ns += __shfl_down(ns, o); }
  __syncthreads();   // reuse red[] safely
  if (lane == 0) { red[wid * 2] = ps; red[wid * 2 + 1] = ns; }
  __syncthreads();
  if (t == 0) {
    float2 v;
    v.x = red[0] + red[2] + red[4] + red[6];
    v.y = red[1] + red[3] + red[5] + red[7];
    parts[p] = v;
  }
}

// ---------------------------------------------------------------------------
// Kernel 3: label histogram + partial reduction + final scalar.
// ---------------------------------------------------------------------------
__global__ __launch_bounds__(1024)
void finalize_kernel(const int* __restrict__ labels,
                     const float2* __restrict__ parts,
                     float* __restrict__ out) {
  __shared__ int cnt[NUM_CLASSES];
  __shared__ float rps[16], rns[16];
  const int t = threadIdx.x;
  if (t < NUM_CLASSES) cnt[t] = 0;
  __syncthreads();
  for (int i = t; i < N_ROWS; i += 1024) atomicAdd(&cnt[labels[i]], 1);

  float ps = 0.f, ns = 0.f;
  for (int i = t; i < NWG; i += 1024) { float2 v = parts[i]; ps += v.x; ns += v.y; }
  #pragma unroll
  for (int o = 32; o; o >>= 1) { ps += __shfl_down(ps, o); ns += __shfl_down(ns, o); }
  if ((t & 63) == 0) { rps[t >> 6] = ps; rns[t >> 6] = ns; }
  __syncthreads();
  if (t == 0) {
    float tps = 0.f, tns = 0.f;
    #pragma unroll
    for (int w = 0; w < 16; ++w) { tps += rps[w]; tns += rns[w]; }
    long long pc = 0;
    for (int c = 0; c < NUM_CLASSES; ++c) pc += (long long)cnt[c] * cnt[c];
    const float fn = (float)((long long)N_ROWS * N_ROWS - pc);
    out[0] = tps / (float)pc + tns / fn;
  }
}

extern "C" void kernel_launch(void* const* d_in, const int* in_sizes, int n_in,
                              void* d_out, int out_size, void* d_ws, size_t ws_size,
                              hipStream_t stream) {
  const float* emb = (const float*)d_in[0];
  const int* labels = (const int*)d_in[1];
  float* out = (float*)d_out;

  unsigned short* en = (unsigned short*)d_ws;                          // 4 MB
  float2* parts = (float2*)((char*)d_ws + (size_t)N_ROWS * DIM * 2);   // 16.6 KB

  normalize_kernel<<<N_ROWS / 4, 256, 0, stream>>>(emb, en);
  sim_loss_kernel<<<NWG, 256, 0, stream>>>(en, labels, parts);
  finalize_kernel<<<1, 1024, 0, stream>>>(labels, parts, out);
}